// Round 1
// baseline (93.994 us; speedup 1.0000x reference)
//
#include <hip/hip_runtime.h>
#include <hip/hip_bf16.h>

typedef __bf16 bf16;
typedef __bf16 bf16x4 __attribute__((ext_vector_type(4)));
typedef __bf16 bf16x8 __attribute__((ext_vector_type(8)));
typedef float f32x4 __attribute__((ext_vector_type(4)));

#define GLOBAL_AS __attribute__((address_space(1)))
#define LDS_AS __attribute__((address_space(3)))

__device__ __forceinline__ void gload_lds16(const void* g, void* l) {
  __builtin_amdgcn_global_load_lds((const GLOBAL_AS void*)g, (LDS_AS void*)l, 16, 0, 0);
}

// ---- prep A: token f32 (16,256,512) -> bf16 flat (4096 x 512) ----
__global__ __launch_bounds__(256) void cvt_token_k(const float* __restrict__ t,
                                                   bf16* __restrict__ o) {
  int base = (blockIdx.x * 256 + threadIdx.x) * 4;
  f32x4 v = *(const f32x4*)(t + base);
  bf16x4 b;
  b[0] = (bf16)v[0]; b[1] = (bf16)v[1]; b[2] = (bf16)v[2]; b[3] = (bf16)v[3];
  *(bf16x4*)(o + base) = b;
}

// ---- prep B: W (512 x 16384) f32 -> Wt (16384 x 512) bf16 (B^T layout) ----
__global__ __launch_bounds__(256) void transpose_w_k(const float* __restrict__ w,
                                                     bf16* __restrict__ wt) {
  __shared__ float tile[32][33];
  int j0 = blockIdx.x * 32;   // 512 blocks over OUT_DIM
  int k0 = blockIdx.y * 32;   // 16 blocks over IN_DIM
  int tx = threadIdx.x & 31;
  int ty = threadIdx.x >> 5;  // 0..7
#pragma unroll
  for (int i = 0; i < 4; ++i)
    tile[ty + i * 8][tx] = w[(size_t)(k0 + ty + i * 8) * 16384 + j0 + tx];
  __syncthreads();
#pragma unroll
  for (int i = 0; i < 4; ++i)
    wt[(size_t)(j0 + ty + i * 8) * 512 + k0 + tx] = (bf16)tile[tx][ty + i * 8];
}

// ---- fused main: GEMM1 (256x128xK512 bf16 MFMA) + bias + silu + rope + GEMM2 ----
// grid (hg=128, b=16), 512 threads = 8 waves (4 row-groups x 2 col-groups)
__global__ __launch_bounds__(512, 2) void fused_main_k(
    const bf16* __restrict__ A, const bf16* __restrict__ Wt,
    const float* __restrict__ bias, float* __restrict__ out) {
  __shared__ char smem[65536];
  // GEMM phase:   A_lds [256][64] bf16 swizzled @0 (32KB), B_lds [128][64] @32768 (16KB)
  // epilogue:     K2 [4][16][256] bf16 swz @0 (32KB), V2 @32768 (32KB)
  // partials:     [8][256] f32 @0 (8KB, after barrier)
  const int tid = threadIdx.x;
  const int lane = tid & 63;
  const int w = tid >> 6;
  const int wr = w >> 1;   // 0..3 (row group, 64 rows)
  const int wc = w & 1;    // 0..1 (col group, 64 cols)
  const int b = blockIdx.y;
  const int hg = blockIdx.x;
  const int m0 = b << 8;
  const int j0 = hg << 7;

  f32x4 acc[4][4] = {};

  for (int ks = 0; ks < 8; ++ks) {
    const int kbase = ks << 6;
    // stage A tile 256x64 (2048 x 16B chunks); source pre-swizzled, LDS linear
#pragma unroll
    for (int i = 0; i < 4; ++i) {
      int q = (i * 8 + w) * 64 + lane;
      int r = q >> 3;
      int cc = (q & 7) ^ (r & 7);
      gload_lds16(A + (size_t)(m0 + r) * 512 + kbase + cc * 8,
                  smem + (i * 8 + w) * 1024);
    }
    // stage B tile 128x64 (1024 chunks)
#pragma unroll
    for (int i = 0; i < 2; ++i) {
      int q = (i * 8 + w) * 64 + lane;
      int r = q >> 3;
      int cc = (q & 7) ^ (r & 7);
      gload_lds16(Wt + (size_t)(j0 + r) * 512 + kbase + cc * 8,
                  smem + 32768 + (i * 8 + w) * 1024);
    }
    __syncthreads();
#pragma unroll
    for (int kk = 0; kk < 2; ++kk) {
      const int cbyte = (kk * 32 + (lane >> 4) * 8) * 2;
      bf16x8 af[4], bfr[4];
#pragma unroll
      for (int mf = 0; mf < 4; ++mf) {
        int r = wr * 64 + mf * 16 + (lane & 15);
        af[mf] = *(const bf16x8*)(smem + r * 128 + (cbyte ^ ((r & 7) << 4)));
      }
#pragma unroll
      for (int nf = 0; nf < 4; ++nf) {
        int r = wc * 64 + nf * 16 + (lane & 15);
        bfr[nf] = *(const bf16x8*)(smem + 32768 + r * 128 + (cbyte ^ ((r & 7) << 4)));
      }
#pragma unroll
      for (int mf = 0; mf < 4; ++mf)
#pragma unroll
        for (int nf = 0; nf < 4; ++nf)
          acc[mf][nf] = __builtin_amdgcn_mfma_f32_16x16x32_bf16(
              af[mf], bfr[nf], acc[mf][nf], 0, 0, 0);
    }
    __syncthreads();
  }

  // ---- epilogue: bias + silu + rope on k-half; write k/v bf16 to LDS [h][d][n] ----
#pragma unroll
  for (int nf = 0; nf < 4; ++nf) {
    const int col = wc * 64 + nf * 16 + (lane & 15);  // 0..127
    const int hl = col >> 5;                          // 0..3 local head
    const int dd = lane & 15;                         // d within 16
    const bool isk = ((nf & 1) == 0);                 // cols d<16 are k
    const float bv = bias[j0 + col];
    float freq = 0.f, sgn = 0.f;
    if (isk) {
      const int t = dd >> 1;
      const int hglob = (hg << 2) + hl;
      freq = exp2f((float)(hglob * 8 + t) * (-13.287712379549449f / 4096.0f));
      sgn = (dd & 1) ? 1.0f : -1.0f;
    }
#pragma unroll
    for (int mf = 0; mf < 4; ++mf) {
      const int n0 = wr * 64 + mf * 16 + ((lane >> 4) << 2);
      f32x4 c = acc[mf][nf];
#pragma unroll
      for (int j = 0; j < 4; ++j) {
        float x = c[j] + bv;
        if (isk) x = x * __builtin_amdgcn_rcpf(1.0f + __expf(-x));  // silu
        c[j] = x;
      }
      if (isk) {
#pragma unroll
        for (int j = 0; j < 4; ++j) {
          float partner = __shfl_xor(c[j], 1);  // pre-update value, lockstep
          float sv, cv;
          __sincosf(freq * (float)(255 - (n0 + j)), &sv, &cv);
          c[j] = c[j] * cv + sgn * partner * sv;
        }
      }
      bf16x4 pk;
      pk[0] = (bf16)c[0]; pk[1] = (bf16)c[1]; pk[2] = (bf16)c[2]; pk[3] = (bf16)c[3];
      int byte = (isk ? 0 : 32768) + hl * 8192 + dd * 512 + n0 * 2;
      byte ^= ((dd & 7) << 4);  // bank swizzle
      *(bf16x4*)(smem + byte) = pk;
    }
  }
  __syncthreads();

  // ---- GEMM2: wave w -> head hl=w>>1, n-half=w&1; 4 MFMAs over 128 n ----
  {
    const int hl = w >> 1;
    const int half = w & 1;
    const int dd = lane & 15;
    f32x4 d2 = {0.f, 0.f, 0.f, 0.f};
#pragma unroll
    for (int kk = 0; kk < 4; ++kk) {
      const int n0 = half * 128 + kk * 32 + ((lane >> 4) << 3);
      int byte = hl * 8192 + dd * 512 + n0 * 2;
      byte ^= ((dd & 7) << 4);
      bf16x8 ka = *(const bf16x8*)(smem + byte);           // A = k^T: [d][n]
      bf16x8 vb = *(const bf16x8*)(smem + 32768 + byte);   // B = v:   [e][n]
      d2 = __builtin_amdgcn_mfma_f32_16x16x32_bf16(ka, vb, d2, 0, 0, 0);
    }
    __syncthreads();  // all K2/V2 reads done before overwriting with partials
    float* part = (float*)smem;  // [8][256]
#pragma unroll
    for (int j = 0; j < 4; ++j) {
      int de = (((lane >> 4) << 2) + j) * 16 + dd;  // d*16+e
      part[w * 256 + de] = d2[j];
    }
  }
  __syncthreads();

  // ---- combine wave-pair partials, coalesced float4 store ----
  if (tid < 256) {
    const float* part = (const float*)smem;
    f32x4 o;
#pragma unroll
    for (int hl = 0; hl < 4; ++hl)
      o[hl] = part[(2 * hl) * 256 + tid] + part[(2 * hl + 1) * 256 + tid];
    *(f32x4*)(out + (size_t)b * 131072 + (size_t)tid * 512 + hg * 4) = o;
  }
}

extern "C" void kernel_launch(void* const* d_in, const int* in_sizes, int n_in,
                              void* d_out, int out_size, void* d_ws, size_t ws_size,
                              hipStream_t stream) {
  const float* token = (const float*)d_in[0];   // (16,256,512) f32
  const float* W     = (const float*)d_in[1];   // (512,16384) f32
  const float* bias  = (const float*)d_in[2];   // (16384,) f32
  float* out = (float*)d_out;                   // (16,256,512) f32

  bf16* Abf = (bf16*)d_ws;                                   // 4 MB
  bf16* Wt  = (bf16*)((char*)d_ws + (size_t)4 * 1024 * 1024); // 16 MB

  cvt_token_k<<<2048, 256, 0, stream>>>(token, Abf);
  transpose_w_k<<<dim3(512, 16), 256, 0, stream>>>(W, Wt);
  fused_main_k<<<dim3(128, 16), 512, 0, stream>>>(Abf, Wt, bias, out);
}